// Round 7
// baseline (1107.398 us; speedup 1.0000x reference)
//
#include <hip/hip_runtime.h>
#include <hip/hip_bf16.h>

#define T_ 1024
#define D_ 1024
#define H_ 16
#define KV_ 4
#define DH_ 64
#define E_ 8
#define TOPK_ 2
#define F_ 512
#define FS_ 2048
#define L_ 2

typedef unsigned int uint32;
typedef unsigned short u16;
typedef __attribute__((ext_vector_type(8))) short short8;
typedef __attribute__((ext_vector_type(4))) short short4v;
typedef __attribute__((ext_vector_type(4))) float f32x4;

__device__ __forceinline__ short f2bf(float f){   // RNE fp32 -> bf16 bits
  uint32 u = __float_as_uint(f);
  return (short)((u + 0x7fffu + ((u >> 16) & 1u)) >> 16);
}
__device__ __forceinline__ float bf2f(short s){
  return __uint_as_float(((uint32)(unsigned short)s) << 16);
}

__device__ __forceinline__ void split8(const float* src, short8& h8, short8& l8){
  #pragma unroll
  for (int j = 0; j < 8; j++){
    short hi = f2bf(src[j]);
    h8[j] = hi;
    l8[j] = f2bf(src[j] - bf2f(hi));
  }
}

// ---------------- embedding gather + zero residual ----------------
__global__ void k_embed(const int* __restrict__ ids, const float* __restrict__ emb,
                        float* __restrict__ h, float* __restrict__ res){
  int idx = blockIdx.x * 256 + threadIdx.x;
  int t = idx >> 10, d = idx & 1023;
  h[idx] = emb[(size_t)ids[t] * D_ + d];
  res[idx] = 0.f;
}

__global__ void k_zero_i32(int* __restrict__ p, int n){
  int i = blockIdx.x * 64 + threadIdx.x;
  if (i < n) p[i] = 0;
}

// ---------------- weight transpose + bf16 hi/lo split ----------------
// in: [K][N] fp32 (slab z adds K*N), out hi/lo: [N][K] bf16 pair.
__global__ __launch_bounds__(256)
void k_wconvT2(const float* __restrict__ in, u16* __restrict__ outh,
               u16* __restrict__ outl, int K, int N){
  __shared__ float tile[64][65];
  const int kb = blockIdx.y * 64, nb = blockIdx.x * 64;
  const size_t slab = (size_t)blockIdx.z * K * N;
  in += slab; outh += slab; outl += slab;
  int tx = threadIdx.x & 63, ty0 = threadIdx.x >> 6;
  #pragma unroll 4
  for (int uy = ty0; uy < 64; uy += 4)
    tile[uy][tx] = in[(size_t)(kb + uy) * N + nb + tx];
  __syncthreads();
  #pragma unroll 4
  for (int uy = ty0; uy < 64; uy += 4){
    float x = tile[tx][uy];
    short hb = f2bf(x);
    size_t o = (size_t)(nb + uy) * K + kb + tx;
    outh[o] = (u16)hb;
    outl[o] = (u16)f2bf(x - bf2f(hb));
  }
}

// -------- fused: res += h; hn = rms(res)*w  (fp32 for router/gate + bf16 hi/lo) ------
__global__ __launch_bounds__(256)
void k_fused_rms(float* __restrict__ res, const float* __restrict__ h,
                 const float* __restrict__ w, float* __restrict__ out,
                 u16* __restrict__ oh, u16* __restrict__ ol){
  int t = blockIdx.x, tid = threadIdx.x;
  float* rr = res + (size_t)t * D_;
  const float* hr = h + (size_t)t * D_;
  float ss = 0.f;
  float vloc[4];
  #pragma unroll
  for (int u = 0; u < 4; u++){
    int d = tid + u * 256;
    float v = rr[d] + hr[d];
    vloc[u] = v;
    ss += v * v;
  }
  #pragma unroll
  for (int o = 32; o; o >>= 1) ss += __shfl_xor(ss, o);
  __shared__ float red[4];
  if ((tid & 63) == 0) red[tid >> 6] = ss;
  __syncthreads();
  float r = rsqrtf((red[0] + red[1] + red[2] + red[3]) * (1.f / D_) + 1e-6f);
  float* orow = out + (size_t)t * D_;
  #pragma unroll
  for (int u = 0; u < 4; u++){
    int d = tid + u * 256;
    rr[d] = vloc[u];
    float o = vloc[u] * r * w[d];
    orow[d] = o;
    short hb = f2bf(o);
    oh[(size_t)t * D_ + d] = (u16)hb;
    ol[(size_t)t * D_ + d] = (u16)f2bf(o - bf2f(hb));
  }
}

// ---- variant: h = h0 + h1 (K-split partials) ----
__global__ __launch_bounds__(256)
void k_fused_rms2(float* __restrict__ res, const float* __restrict__ h0,
                  const float* __restrict__ h1, const float* __restrict__ w,
                  float* __restrict__ out, u16* __restrict__ oh, u16* __restrict__ ol){
  int t = blockIdx.x, tid = threadIdx.x;
  float* rr = res + (size_t)t * D_;
  const float* h0r = h0 + (size_t)t * D_;
  const float* h1r = h1 + (size_t)t * D_;
  float ss = 0.f;
  float vloc[4];
  #pragma unroll
  for (int u = 0; u < 4; u++){
    int d = tid + u * 256;
    float v = rr[d] + h0r[d] + h1r[d];
    vloc[u] = v;
    ss += v * v;
  }
  #pragma unroll
  for (int o = 32; o; o >>= 1) ss += __shfl_xor(ss, o);
  __shared__ float red[4];
  if ((tid & 63) == 0) red[tid >> 6] = ss;
  __syncthreads();
  float r = rsqrtf((red[0] + red[1] + red[2] + red[3]) * (1.f / D_) + 1e-6f);
  float* orow = out + (size_t)t * D_;
  #pragma unroll
  for (int u = 0; u < 4; u++){
    int d = tid + u * 256;
    rr[d] = vloc[u];
    float o = vloc[u] * r * w[d];
    orow[d] = o;
    short hb = f2bf(o);
    oh[(size_t)t * D_ + d] = (u16)hb;
    ol[(size_t)t * D_ + d] = (u16)f2bf(o - bf2f(hb));
  }
}

// ---------------- per-head RMSNorm + RoPE (in place) ----------------
__global__ __launch_bounds__(64)
void k_qknorm_rope(float* __restrict__ buf, const float* __restrict__ nw,
                   const int* __restrict__ pos, int nheads){
  int row = blockIdx.x;
  int t = row / nheads;
  int lane = threadIdx.x;
  int base = row * DH_ + lane;
  float x = buf[base];
  float ss = x * x;
  #pragma unroll
  for (int o = 32; o; o >>= 1) ss += __shfl_xor(ss, o);
  float r = rsqrtf(ss * (1.f / DH_) + 1e-6f);
  float xn = x * r * nw[lane];
  int j = lane & 31;
  float inv = powf(1.0e6f, -(float)j * (1.f / 32.f));
  float ang = (float)pos[t] * inv;
  float s, c;
  sincosf(ang, &s, &c);
  float p = __shfl_xor(xn, 32);
  float rot = (lane < 32) ? -p : p;
  buf[base] = xn * c + rot * s;
}

// ---------------- MFMA flash attention (bf16 hi/lo output) ----------------
__global__ __launch_bounds__(256)
void k_fattn(const float* __restrict__ q, const float* __restrict__ k,
             const float* __restrict__ v, u16* __restrict__ outh,
             u16* __restrict__ outl){
  const int h = blockIdx.x, qt = blockIdx.y;
  const int kvh = h >> 2;
  const int tid = threadIdx.x;
  const int w = tid >> 6, lane = tid & 63, l16 = lane & 15, lq = lane >> 4;

  __shared__ __align__(16) short Kh[64][72], Kl[64][72];
  __shared__ __align__(16) short Vth[64][72], Vtl[64][72];
  __shared__ __align__(16) short Ph[64][72], Pl[64][72];

  short8 qh[2], ql[2];
  {
    const float* qp = q + ((size_t)(qt * 64 + w * 16 + l16) * H_ + h) * DH_;
    #pragma unroll
    for (int s = 0; s < 2; s++){
      float a8[8];
      *(float4*)&a8[0] = *(const float4*)(qp + lq * 8 + 32 * s);
      *(float4*)&a8[4] = *(const float4*)(qp + lq * 8 + 32 * s + 4);
      split8(a8, qh[s], ql[s]);
    }
  }

  float m_i[4], l_i[4];
  f32x4 acc[4];
  #pragma unroll
  for (int i = 0; i < 4; i++){ m_i[i] = -1e30f; l_i[i] = 0.f; acc[i] = (f32x4){0.f,0.f,0.f,0.f}; }

  const int kc = tid >> 2, kd = (tid & 3) * 16;
  const int vc0 = (tid & 15) * 4, vd0 = (tid >> 4) * 4;
  float kr[16], vr[16];

  {
    const float* kp = k + ((size_t)(0 + kc) * KV_ + kvh) * DH_ + kd;
    #pragma unroll
    for (int u = 0; u < 16; u += 4) *(float4*)&kr[u] = *(const float4*)(kp + u);
    #pragma unroll
    for (int cc = 0; cc < 4; cc++){
      const float* vp = v + ((size_t)(0 + vc0 + cc) * KV_ + kvh) * DH_ + vd0;
      *(float4*)&vr[cc * 4] = *(const float4*)vp;
    }
  }

  for (int kt = 0; kt <= qt; kt++){
    __syncthreads();
    {
      short8 h8, l8;
      split8(&kr[0], h8, l8);
      *(short8*)&Kh[kc][kd] = h8;     *(short8*)&Kl[kc][kd] = l8;
      split8(&kr[8], h8, l8);
      *(short8*)&Kh[kc][kd + 8] = h8; *(short8*)&Kl[kc][kd + 8] = l8;
      #pragma unroll
      for (int dd = 0; dd < 4; dd++){
        short4v hv, lv;
        #pragma unroll
        for (int cc = 0; cc < 4; cc++){
          float f = vr[cc * 4 + dd];
          short hb = f2bf(f);
          hv[cc] = hb;
          lv[cc] = f2bf(f - bf2f(hb));
        }
        *(short4v*)&Vth[vd0 + dd][vc0] = hv;
        *(short4v*)&Vtl[vd0 + dd][vc0] = lv;
      }
    }
    __syncthreads();
    if (kt < qt){
      const float* kp = k + ((size_t)((kt + 1) * 64 + kc) * KV_ + kvh) * DH_ + kd;
      #pragma unroll
      for (int u = 0; u < 16; u += 4) *(float4*)&kr[u] = *(const float4*)(kp + u);
      #pragma unroll
      for (int cc = 0; cc < 4; cc++){
        const float* vp = v + ((size_t)((kt + 1) * 64 + vc0 + cc) * KV_ + kvh) * DH_ + vd0;
        *(float4*)&vr[cc * 4] = *(const float4*)vp;
      }
    }

    f32x4 sa[4];
    #pragma unroll
    for (int ct = 0; ct < 4; ct++) sa[ct] = (f32x4){0.f,0.f,0.f,0.f};
    #pragma unroll
    for (int s = 0; s < 2; s++){
      #pragma unroll
      for (int ct = 0; ct < 4; ct++){
        short8 kh8 = *(const short8*)&Kh[ct * 16 + l16][lq * 8 + 32 * s];
        short8 kl8 = *(const short8*)&Kl[ct * 16 + l16][lq * 8 + 32 * s];
        sa[ct] = __builtin_amdgcn_mfma_f32_16x16x32_bf16(qh[s], kh8, sa[ct], 0, 0, 0);
        sa[ct] = __builtin_amdgcn_mfma_f32_16x16x32_bf16(qh[s], kl8, sa[ct], 0, 0, 0);
        sa[ct] = __builtin_amdgcn_mfma_f32_16x16x32_bf16(ql[s], kh8, sa[ct], 0, 0, 0);
      }
    }

    const bool diag = (kt == qt);
    #pragma unroll
    for (int ct = 0; ct < 4; ct++)
      #pragma unroll
      for (int i = 0; i < 4; i++){
        float sv = sa[ct][i] * 0.125f;
        if (diag && (ct * 16 + l16 > w * 16 + lq * 4 + i)) sv = -1e30f;
        sa[ct][i] = sv;
      }

    #pragma unroll
    for (int i = 0; i < 4; i++){
      float mx = fmaxf(fmaxf(sa[0][i], sa[1][i]), fmaxf(sa[2][i], sa[3][i]));
      #pragma unroll
      for (int o = 8; o; o >>= 1) mx = fmaxf(mx, __shfl_xor(mx, o));
      float mn = fmaxf(m_i[i], mx);
      float al = __expf(m_i[i] - mn);
      float ls = 0.f;
      #pragma unroll
      for (int ct = 0; ct < 4; ct++){
        float pv = __expf(sa[ct][i] - mn);
        sa[ct][i] = pv;
        ls += pv;
      }
      #pragma unroll
      for (int o = 8; o; o >>= 1) ls += __shfl_xor(ls, o);
      l_i[i] = l_i[i] * al + ls;
      m_i[i] = mn;
      #pragma unroll
      for (int dt = 0; dt < 4; dt++) acc[dt][i] *= al;
    }

    {
      int pr = w * 16 + lq * 4;
      #pragma unroll
      for (int i = 0; i < 4; i++)
        #pragma unroll
        for (int ct = 0; ct < 4; ct++){
          float pv = sa[ct][i];
          short hb = f2bf(pv);
          Ph[pr + i][ct * 16 + l16] = hb;
          Pl[pr + i][ct * 16 + l16] = f2bf(pv - bf2f(hb));
        }
    }
    __syncthreads();

    #pragma unroll
    for (int s = 0; s < 2; s++){
      short8 pah = *(const short8*)&Ph[w * 16 + l16][lq * 8 + 32 * s];
      short8 pal = *(const short8*)&Pl[w * 16 + l16][lq * 8 + 32 * s];
      #pragma unroll
      for (int dt = 0; dt < 4; dt++){
        short8 vh8 = *(const short8*)&Vth[dt * 16 + l16][lq * 8 + 32 * s];
        short8 vl8 = *(const short8*)&Vtl[dt * 16 + l16][lq * 8 + 32 * s];
        acc[dt] = __builtin_amdgcn_mfma_f32_16x16x32_bf16(pah, vh8, acc[dt], 0, 0, 0);
        acc[dt] = __builtin_amdgcn_mfma_f32_16x16x32_bf16(pah, vl8, acc[dt], 0, 0, 0);
        acc[dt] = __builtin_amdgcn_mfma_f32_16x16x32_bf16(pal, vh8, acc[dt], 0, 0, 0);
      }
    }
  }

  int orow = qt * 64 + w * 16 + lq * 4;
  #pragma unroll
  for (int i = 0; i < 4; i++){
    float inv = 1.f / l_i[i];
    #pragma unroll
    for (int dt = 0; dt < 4; dt++){
      size_t oidx = (size_t)(orow + i) * (H_ * DH_) + h * DH_ + dt * 16 + l16;
      float o = acc[dt][i] * inv;
      short hb = f2bf(o);
      outh[oidx] = (u16)hb;
      outl[oidx] = (u16)f2bf(o - bf2f(hb));
    }
  }
}

// ======= bf16 MFMA GEMM core v4: pre-split A (hi/lo) AND B (hi/lo), 3-MFMA rule =======
// Bit-identical accumulation to the round-4 verified core (ah*bh + ah*bl + al*bh),
// with all fp32->bf16 splits hoisted to producers. Zero conversion VALU in-loop.
#define GEMM_LDS4  __shared__ __align__(16) short Ah[64][40], Al[64][40], Bh[64][40], Bl[64][40]

#define GEMM_BODY4(ARH, ARL, BRH, BRL, KBASE, KH, AOK)                                        \
  f32x4 acc[4] = {};                                                                          \
  {                                                                                           \
    int tid = threadIdx.x;                                                                    \
    int w_ = tid >> 6, lane_ = tid & 63, l16_ = lane_ & 15, lq_ = lane_ >> 4;                 \
    int sm_ = tid & 63, sk_ = (tid >> 6) * 8;                                                 \
    const u16* pAh = (ARH) + (KBASE) + sk_;                                                   \
    const u16* pAl = (ARL) + (KBASE) + sk_;                                                   \
    const u16* pBh = (BRH) + (KBASE) + sk_;                                                   \
    const u16* pBl = (BRL) + (KBASE) + sk_;                                                   \
    short8 a_h = {}, a_l = {}, b_h, b_l;                                                      \
    if (AOK){ a_h = *(const short8*)pAh; a_l = *(const short8*)pAl; }                         \
    b_h = *(const short8*)pBh;                                                                \
    b_l = *(const short8*)pBl;                                                                \
    int nc = (KH) >> 5;                                                                       \
    for (int c = 0; c < nc; c++){                                                             \
      *(short8*)&Ah[sm_][sk_] = a_h;                                                          \
      *(short8*)&Al[sm_][sk_] = a_l;                                                          \
      *(short8*)&Bh[sm_][sk_] = b_h;                                                          \
      *(short8*)&Bl[sm_][sk_] = b_l;                                                          \
      __syncthreads();                                                                        \
      if (c + 1 < nc){                                                                        \
        if (AOK){                                                                             \
          a_h = *(const short8*)(pAh + (c + 1) * 32);                                         \
          a_l = *(const short8*)(pAl + (c + 1) * 32);                                         \
        }                                                                                     \
        b_h = *(const short8*)(pBh + (c + 1) * 32);                                           \
        b_l = *(const short8*)(pBl + (c + 1) * 32);                                           \
      }                                                                                       \
      short8 fa = *(const short8*)&Ah[w_ * 16 + l16_][lq_ * 8];                               \
      short8 fl = *(const short8*)&Al[w_ * 16 + l16_][lq_ * 8];                               \
      _Pragma("unroll")                                                                       \
      for (int nt = 0; nt < 4; nt++){                                                         \
        short8 fbh = *(const short8*)&Bh[nt * 16 + l16_][lq_ * 8];                            \
        short8 fbl = *(const short8*)&Bl[nt * 16 + l16_][lq_ * 8];                            \
        acc[nt] = __builtin_amdgcn_mfma_f32_16x16x32_bf16(fa, fbh, acc[nt], 0, 0, 0);         \
        acc[nt] = __builtin_amdgcn_mfma_f32_16x16x32_bf16(fa, fbl, acc[nt], 0, 0, 0);         \
        acc[nt] = __builtin_amdgcn_mfma_f32_16x16x32_bf16(fl, fbh, acc[nt], 0, 0, 0);         \
      }                                                                                       \
      __syncthreads();                                                                        \
    }                                                                                         \
  }

// ---------------- generic: C[M,N] = A[M,K] @ B^T[N,K] ----------------
__global__ __launch_bounds__(256)
void k_bgemm(const u16* __restrict__ A_h, const u16* __restrict__ A_l,
             const u16* __restrict__ Bth, const u16* __restrict__ Btl,
             float* __restrict__ C, int M, int N, int K){
  GEMM_LDS4;
  int row0 = blockIdx.y * 64, col0 = blockIdx.x * 64;
  int sm = threadIdx.x & 63;
  bool aok = (row0 + sm) < M;
  const u16* Ar = A_h + (size_t)(row0 + sm) * K;
  const u16* Lr = A_l + (size_t)(row0 + sm) * K;
  const u16* Bch = Bth + (size_t)(col0 + sm) * K;
  const u16* Bcl = Btl + (size_t)(col0 + sm) * K;
  GEMM_BODY4(Ar, Lr, Bch, Bcl, 0, K, aok);
  int w = threadIdx.x >> 6, lane = threadIdx.x & 63, l16 = lane & 15, lq = lane >> 4;
  #pragma unroll
  for (int nt = 0; nt < 4; nt++)
    #pragma unroll
    for (int i = 0; i < 4; i++){
      int r = row0 + w * 16 + lq * 4 + i;
      if (r < M) C[(size_t)r * N + col0 + nt * 16 + l16] = acc[nt][i];
    }
}

// ---------------- K-split x2 generic ----------------
__global__ __launch_bounds__(256)
void k_bgemm_ks2(const u16* __restrict__ A_h, const u16* __restrict__ A_l,
                 const u16* __restrict__ Bth, const u16* __restrict__ Btl,
                 float* __restrict__ C0, float* __restrict__ C1,
                 int M, int N, int K){
  GEMM_LDS4;
  int row0 = blockIdx.y * 64, col0 = blockIdx.x * 64;
  int z = blockIdx.z, KH = K >> 1;
  int sm = threadIdx.x & 63;
  bool aok = (row0 + sm) < M;
  const u16* Ar = A_h + (size_t)(row0 + sm) * K;
  const u16* Lr = A_l + (size_t)(row0 + sm) * K;
  const u16* Bch = Bth + (size_t)(col0 + sm) * K;
  const u16* Bcl = Btl + (size_t)(col0 + sm) * K;
  GEMM_BODY4(Ar, Lr, Bch, Bcl, z * KH, KH, aok);
  float* C = z ? C1 : C0;
  int w = threadIdx.x >> 6, lane = threadIdx.x & 63, l16 = lane & 15, lq = lane >> 4;
  #pragma unroll
  for (int nt = 0; nt < 4; nt++)
    #pragma unroll
    for (int i = 0; i < 4; i++){
      int r = row0 + w * 16 + lq * 4 + i;
      if (r < M) C[(size_t)r * N + col0 + nt * 16 + l16] = acc[nt][i];
    }
}

// ---------------- fused QKV: col-block selects wq/wk/wv (all B^T stride = D) ----------
__global__ __launch_bounds__(256)
void k_bgemm_qkv(const u16* __restrict__ hn_h, const u16* __restrict__ hn_l,
                 const u16* __restrict__ wqh, const u16* __restrict__ wql,
                 const u16* __restrict__ wkh, const u16* __restrict__ wkl,
                 const u16* __restrict__ wvh, const u16* __restrict__ wvl,
                 float* __restrict__ qlin, float* __restrict__ kbuf,
                 float* __restrict__ vbuf){
  GEMM_LDS4;
  int cb = blockIdx.x;
  const u16 *Bth, *Btl; float* C; int N; int col0;
  if (cb < 16){ Bth = wqh; Btl = wql; C = qlin; N = H_ * DH_; col0 = cb * 64; }
  else if (cb < 20){ Bth = wkh; Btl = wkl; C = kbuf; N = KV_ * DH_; col0 = (cb - 16) * 64; }
  else { Bth = wvh; Btl = wvl; C = vbuf; N = KV_ * DH_; col0 = (cb - 20) * 64; }
  int row0 = blockIdx.y * 64;
  int sm = threadIdx.x & 63;
  const u16* Ar = hn_h + (size_t)(row0 + sm) * D_;
  const u16* Lr = hn_l + (size_t)(row0 + sm) * D_;
  const u16* Bch = Bth + (size_t)(col0 + sm) * D_;
  const u16* Bcl = Btl + (size_t)(col0 + sm) * D_;
  GEMM_BODY4(Ar, Lr, Bch, Bcl, 0, D_, true);
  int w = threadIdx.x >> 6, lane = threadIdx.x & 63, l16 = lane & 15, lq = lane >> 4;
  #pragma unroll
  for (int nt = 0; nt < 4; nt++)
    #pragma unroll
    for (int i = 0; i < 4; i++){
      int r = row0 + w * 16 + lq * 4 + i;
      C[(size_t)r * N + col0 + nt * 16 + l16] = acc[nt][i];
    }
}

// ---------------- expert up, K-split x2 (gathered A rows) ----------------
__global__ __launch_bounds__(256)
void k_bgemm_up(const u16* __restrict__ hn_h, const u16* __restrict__ hn_l,
                const u16* __restrict__ eguh, const u16* __restrict__ egul,
                float* __restrict__ G0, float* __restrict__ G1,
                const int* __restrict__ counts, const int* __restrict__ offsets,
                const int* __restrict__ rowtok){
  const int z = blockIdx.z;
  const int e = z >> 1, s = z & 1;
  const int me = counts[e];
  const int row0 = blockIdx.y * 64;
  if (row0 >= me) return;
  const int off = offsets[e];
  const int N = 2 * F_, KH = D_ >> 1;
  GEMM_LDS4;
  int col0 = blockIdx.x * 64;
  int sm = threadIdx.x & 63;
  bool aok = (row0 + sm) < me;
  int tok = aok ? rowtok[off + row0 + sm] : 0;
  const u16* Ar = hn_h + (size_t)tok * D_;
  const u16* Lr = hn_l + (size_t)tok * D_;
  const u16* Bch = eguh + ((size_t)e * (2 * F_) + col0 + sm) * D_;
  const u16* Bcl = egul + ((size_t)e * (2 * F_) + col0 + sm) * D_;
  GEMM_BODY4(Ar, Lr, Bch, Bcl, s * KH, KH, aok);
  float* G = s ? G1 : G0;
  int w = threadIdx.x >> 6, lane = threadIdx.x & 63, l16 = lane & 15, lq = lane >> 4;
  #pragma unroll
  for (int nt = 0; nt < 4; nt++)
    #pragma unroll
    for (int i = 0; i < 4; i++){
      int r = row0 + w * 16 + lq * 4 + i;
      if (r < me) G[(size_t)(off + r) * N + col0 + nt * 16 + l16] = acc[nt][i];
    }
}

// ---------------- expert down, K-split x2: + weighted scatter-add ----------------
__global__ __launch_bounds__(256)
void k_bgemm_dn(const u16* __restrict__ he_h, const u16* __restrict__ he_l,
                const u16* __restrict__ ednh, const u16* __restrict__ ednl,
                float* __restrict__ routed, const int* __restrict__ counts,
                const int* __restrict__ offsets, const int* __restrict__ rowtok,
                const float* __restrict__ roww){
  const int z = blockIdx.z;
  const int e = z >> 1, s = z & 1;
  const int me = counts[e];
  const int row0 = blockIdx.y * 64;
  if (row0 >= me) return;
  const int off = offsets[e];
  const int KH = F_ >> 1;
  GEMM_LDS4;
  int col0 = blockIdx.x * 64;
  int sm = threadIdx.x & 63;
  bool aok = (row0 + sm) < me;
  const u16* Ar = he_h + (size_t)(off + row0 + (aok ? sm : 0)) * F_;
  const u16* Lr = he_l + (size_t)(off + row0 + (aok ? sm : 0)) * F_;
  const u16* Bch = ednh + ((size_t)e * D_ + col0 + sm) * F_;
  const u16* Bcl = ednl + ((size_t)e * D_ + col0 + sm) * F_;
  GEMM_BODY4(Ar, Lr, Bch, Bcl, s * KH, KH, aok);
  int w = threadIdx.x >> 6, lane = threadIdx.x & 63, l16 = lane & 15, lq = lane >> 4;
  #pragma unroll
  for (int i = 0; i < 4; i++){
    int r = row0 + w * 16 + lq * 4 + i;
    if (r < me){
      int tok = rowtok[off + r];
      float wgt = roww[off + r];
      float* cp = routed + (size_t)tok * D_ + col0;
      #pragma unroll
      for (int nt = 0; nt < 4; nt++)
        atomicAdd(&cp[nt * 16 + l16], wgt * acc[nt][i]);
    }
  }
}

// ---------------- SiLU(gate)*up -> bf16 hi/lo ----------------
__global__ void k_silumul(const float* __restrict__ g, u16* __restrict__ oh,
                          u16* __restrict__ ol, int width, int half){
  int idx = blockIdx.x * 256 + threadIdx.x;
  int r = idx / half, f = idx - r * half;
  float a = g[(size_t)r * width + f];
  float b = g[(size_t)r * width + half + f];
  float val = a * b / (1.f + __expf(-a));
  short hb = f2bf(val);
  oh[idx] = (u16)hb;
  ol[idx] = (u16)f2bf(val - bf2f(hb));
}

// ---- SiLU(gate)*up over summed K-split partials -> bf16 hi/lo ----
__global__ void k_silumul2(const float* __restrict__ g0, const float* __restrict__ g1,
                           u16* __restrict__ oh, u16* __restrict__ ol,
                           int width, int half){
  int idx = blockIdx.x * 256 + threadIdx.x;
  int r = idx / half, f = idx - r * half;
  size_t ia = (size_t)r * width + f, ib = (size_t)r * width + half + f;
  float a = g0[ia] + g1[ia];
  float b = g0[ib] + g1[ib];
  float val = a * b / (1.f + __expf(-a));
  short hb = f2bf(val);
  oh[idx] = (u16)hb;
  ol[idx] = (u16)f2bf(val - bf2f(hb));
}

// ---------------- shared-expert sigmoid gate (fp32 hn, round-4 path) ----------------
__global__ __launch_bounds__(256)
void k_gate(const float* __restrict__ hn, const float* __restrict__ sg,
            float* __restrict__ gate){
  int t = blockIdx.x, tid = threadIdx.x;
  const float* xr = hn + (size_t)t * D_;
  float s = 0.f;
  for (int d = tid; d < D_; d += 256) s += xr[d] * sg[d];
  #pragma unroll
  for (int o = 32; o; o >>= 1) s += __shfl_xor(s, o);
  __shared__ float red[4];
  if ((tid & 63) == 0) red[tid >> 6] = s;
  __syncthreads();
  if (tid == 0){
    float tot = red[0] + red[1] + red[2] + red[3];
    gate[t] = 1.f / (1.f + __expf(-tot));
  }
}

// ---------------- router: softmax + top-2 + renorm (fp32 hn, round-4 path) ----------
__global__ __launch_bounds__(64)
void k_router(const float* __restrict__ hn, const float* __restrict__ rw,
              int* __restrict__ counts, int* __restrict__ top_e,
              float* __restrict__ top_w){
  int t = blockIdx.x;
  int lane = threadIdx.x;
  int e = lane & 7, c = lane >> 3;
  const float* xr = hn + (size_t)t * D_;
  float s = 0.f;
  for (int d = c * 128; d < c * 128 + 128; d++) s += xr[d] * rw[d * E_ + e];
  s += __shfl_down(s, 32);
  s += __shfl_down(s, 16);
  s += __shfl_down(s, 8);
  float v[8];
  #pragma unroll
  for (int qq = 0; qq < 8; qq++) v[qq] = __shfl(s, qq);
  if (lane == 0){
    float mx = v[0];
    #pragma unroll
    for (int qq = 1; qq < 8; qq++) mx = fmaxf(mx, v[qq]);
    float p[8];
    #pragma unroll
    for (int qq = 0; qq < 8; qq++) p[qq] = __expf(v[qq] - mx);
    int i0 = 0;
    #pragma unroll
    for (int qq = 1; qq < 8; qq++) if (p[qq] > p[i0]) i0 = qq;
    int i1 = (i0 == 0) ? 1 : 0;
    #pragma unroll
    for (int qq = 0; qq < 8; qq++) if (qq != i0 && p[qq] > p[i1]) i1 = qq;
    float w0 = p[i0], w1 = p[i1];
    float inv = 1.f / (w0 + w1);
    top_e[t * 2 + 0] = i0; top_w[t * 2 + 0] = w0 * inv;
    top_e[t * 2 + 1] = i1; top_w[t * 2 + 1] = w1 * inv;
    atomicAdd(&counts[i0], 1);
    atomicAdd(&counts[i1], 1);
  }
}

__global__ void k_prefix(const int* __restrict__ counts, int* __restrict__ offsets,
                         int* __restrict__ cursor){
  if (threadIdx.x == 0 && blockIdx.x == 0){
    int acc = 0;
    for (int e = 0; e < E_; e++){ offsets[e] = acc; cursor[e] = acc; acc += counts[e]; }
  }
}

__global__ void k_assign(const int* __restrict__ top_e, const float* __restrict__ top_w,
                         int* __restrict__ cursor, int* __restrict__ rowtok,
                         float* __restrict__ roww){
  int i = blockIdx.x * 256 + threadIdx.x;
  if (i >= T_ * TOPK_) return;
  int e = top_e[i];
  int slot = atomicAdd(&cursor[e], 1);
  rowtok[slot] = i >> 1;
  roww[slot] = top_w[i];
}

// ---- h = (p0 + p1) * gate[t]  (sdn K-split partials; experts scatter-add on top) ----
__global__ void k_prefill2(float* __restrict__ h, const float* __restrict__ p0,
                           const float* __restrict__ p1, const float* __restrict__ gate){
  int idx = blockIdx.x * 256 + threadIdx.x;
  h[idx] = (p0[idx] + p1[idx]) * gate[idx >> 10];
}

// ---------------- final: out = rms(res + h, final_ln), fp32 out ----------------
__global__ __launch_bounds__(256)
void k_final_rms(const float* __restrict__ resv, const float* __restrict__ hv,
                 const float* __restrict__ w, float* __restrict__ out){
  int t = blockIdx.x, tid = threadIdx.x;
  const float* xr = resv + (size_t)t * D_;
  const float* hr = hv + (size_t)t * D_;
  float ss = 0.f;
  for (int d = tid; d < D_; d += 256){ float v = xr[d] + hr[d]; ss += v * v; }
  #pragma unroll
  for (int o = 32; o; o >>= 1) ss += __shfl_xor(ss, o);
  __shared__ float red[4];
  if ((tid & 63) == 0) red[tid >> 6] = ss;
  __syncthreads();
  float r = rsqrtf((red[0] + red[1] + red[2] + red[3]) * (1.f / D_) + 1e-6f);
  float* orow = out + (size_t)t * D_;
  for (int d = tid; d < D_; d += 256) orow[d] = (xr[d] + hr[d]) * r * w[d];
}

extern "C" void kernel_launch(void* const* d_in, const int* in_sizes, int n_in,
                              void* d_out, int out_size, void* d_ws, size_t ws_size,
                              hipStream_t stream){
  (void)in_sizes; (void)n_in; (void)out_size; (void)ws_size;
  const int* ids = (const int*)d_in[0];
  const int* pos = (const int*)d_in[1];
  const float* emb = (const float*)d_in[2];
  const float* ln1 = (const float*)d_in[3];
  const float* wq  = (const float*)d_in[4];
  const float* wk  = (const float*)d_in[5];
  const float* wv  = (const float*)d_in[6];
  const float* wo  = (const float*)d_in[7];
  const float* qn  = (const float*)d_in[8];
  const float* kn  = (const float*)d_in[9];
  const float* ln2 = (const float*)d_in[10];
  const float* rw  = (const float*)d_in[11];
  const float* egu = (const float*)d_in[12];
  const float* edn = (const float*)d_in[13];
  const float* sgu = (const float*)d_in[14];
  const float* sdn = (const float*)d_in[15];
  const float* sg  = (const float*)d_in[16];
  const float* fln = (const float*)d_in[17];

  // ---- workspace map: activations 17 Mf (round-4-proven) + hn hi/lo + 8 Mf weight
  //      region at [18.25,26.25) Mf.  Total 105 MB <= 114 MB proven by round-5/6
  //      identical-error analysis (round 5's writes up to 114 MB landed intact). ----
  float* ws = (float*)d_ws;
  const size_t MB = (size_t)1 << 20;   // 1M floats
  float* res    = ws;                  // [0,1)
  float* h      = ws + 1 * MB;         // [1,2)
  float* hn     = ws + 2 * MB;         // [2,3) fp32 (router/gate, round-4 path)
  float* qlin   = ws + 3 * MB;         // [3,4) attn phase
  float* kbuf   = ws + 4 * MB;         // [4,5) attn phase
  float* vbuf   = kbuf + T_ * KV_ * DH_;
  u16* attnb_h  = (u16*)(ws + 5 * MB); // [5,6)
  u16* attnb_l  = attnb_h + (T_ * H_ * DH_);
  float* gu     = ws + 6 * MB;         // [6,10)
  u16* sact_h   = (u16*)(ws + 10 * MB);// [10,12)
  u16* sact_l   = sact_h + (T_ * FS_);
  float* ps0    = ws + 12 * MB;        // [12,13)
  float* G0     = ws + 13 * MB;        // [13,15)
  u16* he_h     = (u16*)(ws + 15 * MB);// [15,16)
  u16* he_l     = he_h + (T_ * TOPK_ * F_);
  float* ps1    = ws + 16 * MB;        // [16,17)
  u16* hn_h     = (u16*)(ws + 17 * MB);// [17,18)
  u16* hn_l     = hn_h + (T_ * D_);
  float* gate   = ws + 18 * MB;        // tail scalars [18,18.02)
  float* roww   = gate + 4096;
  float* top_w  = roww + 4096;
  int* counts   = (int*)(top_w + 4096);
  int* offsets  = counts + 8;
  int* cursor   = offsets + 8;
  int* top_e    = cursor + 8;
  int* rowtok   = top_e + 2048;
  // dedicated weight region: 16M u16 = 8 Mf at [18.25, 26.25)
  u16* W = (u16*)(ws + 18 * MB + (MB >> 2));
  // attn set (5M u16): wq hi/lo, wk hi/lo, wv hi/lo, wo hi/lo
  u16* wq_th = W;                  u16* wq_tl = W + (1u << 20);
  u16* wk_th = W + (2u << 20);     u16* wk_tl = wk_th + (1u << 18);
  u16* wv_th = wk_th + (1u << 19); u16* wv_tl = wv_th + (1u << 18);
  u16* wo_th = W + (3u << 20);     u16* wo_tl = W + (4u << 20);
  // shared set (reuses W after attn GEMMs): sgu 8M u16, then sdn 4M u16
  u16* sgu_th = W;                 u16* sgu_tl = W + (4u << 20);
  u16* sdn_th = W;                 u16* sdn_tl = W + (2u << 20);
  // expert set (reuses W): egu 16M u16, then edn 8M u16
  u16* egu_th = W;                 u16* egu_tl = W + (8u << 20);
  u16* edn_th = W;                 u16* edn_tl = W + (4u << 20);
  // fp32 partial reuse:
  float* pw0 = ws + 3 * MB;            // wo partials (attn phase; qlin dead post-fattn)
  float* pw1 = ws + 4 * MB;
  float* G1  = ws + 3 * MB;            // expert-up partial 1 ([3,5) dead in MoE phase)

  const int NTD = T_ * D_ / 256;

  k_embed<<<NTD, 256, 0, stream>>>(ids, emb, h, res);

  for (int i = 0; i < L_; i++){
    // ---- attn weights hi/lo convert (W free: prev layer's edn consumed) ----
    k_wconvT2<<<dim3(16, 16, 1), 256, 0, stream>>>(wq + (size_t)i * D_ * (H_ * DH_), wq_th, wq_tl, D_, H_ * DH_);
    k_wconvT2<<<dim3(4, 16, 1), 256, 0, stream>>>(wk + (size_t)i * D_ * (KV_ * DH_), wk_th, wk_tl, D_, KV_ * DH_);
    k_wconvT2<<<dim3(4, 16, 1), 256, 0, stream>>>(wv + (size_t)i * D_ * (KV_ * DH_), wv_th, wv_tl, D_, KV_ * DH_);
    k_wconvT2<<<dim3(16, 16, 1), 256, 0, stream>>>(wo + (size_t)i * (H_ * DH_) * D_, wo_th, wo_tl, H_ * DH_, D_);
    // ---- attention ----
    k_fused_rms<<<T_, 256, 0, stream>>>(res, h, ln1 + (size_t)i * D_, hn, hn_h, hn_l);
    k_bgemm_qkv<<<dim3(24, 16), 256, 0, stream>>>(hn_h, hn_l, wq_th, wq_tl, wk_th, wk_tl,
                                                  wv_th, wv_tl, qlin, kbuf, vbuf);
    k_qknorm_rope<<<T_ * H_, 64, 0, stream>>>(qlin, qn + (size_t)i * DH_, pos, H_);
    k_qknorm_rope<<<T_ * KV_, 64, 0, stream>>>(kbuf, kn + (size_t)i * DH_, pos, KV_);
    k_fattn<<<dim3(H_, T_ / 64), 256, 0, stream>>>(qlin, kbuf, vbuf, attnb_h, attnb_l);
    k_bgemm_ks2<<<dim3(16, 16, 2), 256, 0, stream>>>(attnb_h, attnb_l, wo_th, wo_tl,
                                                     pw0, pw1, T_, D_, H_ * DH_);
    // ---- MoE MLP ----
    k_fused_rms2<<<T_, 256, 0, stream>>>(res, pw0, pw1, ln2 + (size_t)i * D_, hn, hn_h, hn_l);
    // shared-expert weights (W reuse after qkv/wo GEMMs done)
    k_wconvT2<<<dim3(64, 16, 1), 256, 0, stream>>>(sgu + (size_t)i * D_ * (2 * FS_), sgu_th, sgu_tl, D_, 2 * FS_);
    k_bgemm<<<dim3(64, 16), 256, 0, stream>>>(hn_h, hn_l, sgu_th, sgu_tl, gu, T_, 2 * FS_, D_);
    k_wconvT2<<<dim3(16, 32, 1), 256, 0, stream>>>(sdn + (size_t)i * FS_ * D_, sdn_th, sdn_tl, FS_, D_);
    k_silumul<<<T_ * FS_ / 256, 256, 0, stream>>>(gu, sact_h, sact_l, 2 * FS_, FS_);
    k_bgemm_ks2<<<dim3(16, 16, 2), 256, 0, stream>>>(sact_h, sact_l, sdn_th, sdn_tl,
                                                     ps0, ps1, T_, D_, FS_);
    // router + gate (fp32 hn)
    k_gate<<<T_, 256, 0, stream>>>(hn, sg + (size_t)i * D_, gate);
    k_zero_i32<<<1, 64, 0, stream>>>(counts, 8);
    k_router<<<T_, 64, 0, stream>>>(hn, rw + (size_t)i * D_ * E_, counts, top_e, top_w);
    k_prefix<<<1, 1, 0, stream>>>(counts, offsets, cursor);
    k_assign<<<8, 256, 0, stream>>>(top_e, top_w, cursor, rowtok, roww);
    k_prefill2<<<NTD, 256, 0, stream>>>(h, ps0, ps1, gate);
    // routed experts (W reuse after sdn GEMM done)
    k_wconvT2<<<dim3(16, 16, E_), 256, 0, stream>>>(egu + (size_t)i * E_ * D_ * (2 * F_), egu_th, egu_tl, D_, 2 * F_);
    k_bgemm_up<<<dim3(16, 32, 16), 256, 0, stream>>>(hn_h, hn_l, egu_th, egu_tl,
                                                     G0, G1, counts, offsets, rowtok);
    k_silumul2<<<T_ * TOPK_ * F_ / 256, 256, 0, stream>>>(G0, G1, he_h, he_l, 2 * F_, F_);
    k_wconvT2<<<dim3(16, 8, E_), 256, 0, stream>>>(edn + (size_t)i * E_ * F_ * D_, edn_th, edn_tl, F_, D_);
    k_bgemm_dn<<<dim3(16, 32, 16), 256, 0, stream>>>(he_h, he_l, edn_th, edn_tl,
                                                     h, counts, offsets, rowtok, roww);
  }

  k_final_rms<<<T_, 256, 0, stream>>>(res, h, fln, (float*)d_out);
}